// Round 9
// baseline (174.215 us; speedup 1.0000x reference)
//
#include <hip/hip_runtime.h>
#include <hip/hip_bf16.h>

// Problem constants: B=8, S=1024, E=1024, H=16, D=64
#define PB 8
#define PS 1024
#define PE 1024
#define PH 16
#define PD 64
#define EPSLN 1e-3f
// softmax scale folded into Wq: SCALE * log2(e), so P = 2^s via raw v_exp_f32
#define QSCALE 0.04508422f   // (1/32) * 1.4426950408889634

typedef __attribute__((ext_vector_type(8))) short bf16x8;    // 8 bf16 = 4 VGPR
typedef __attribute__((ext_vector_type(4))) float f32x4;
typedef __attribute__((ext_vector_type(16))) float f32x16;

__device__ __forceinline__ unsigned short f2bf(float f) {
    unsigned int u = __float_as_uint(f);
    u += 0x7FFFu + ((u >> 16) & 1u);   // RNE
    return (unsigned short)(u >> 16);
}

__device__ __forceinline__ void gload_lds16(const void* g, void* l) {
    __builtin_amdgcn_global_load_lds(
        (const __attribute__((address_space(1))) unsigned int*)g,
        (__attribute__((address_space(3))) unsigned int*)l,
        16, 0, 0);
}

__device__ __forceinline__ unsigned int cvtpk_bf16(float lo, float hi) {
    unsigned int r;
    asm("v_cvt_pk_bf16_f32 %0, %1, %2" : "=v"(r) : "v"(lo), "v"(hi));
    return r;
}

__device__ __forceinline__ void plswap(unsigned int& a, unsigned int& b) {
    asm("v_permlane32_swap_b32 %0, %1" : "+v"(a), "+v"(b));
}

// raw hardware 2^x — no OCML denormal fix-up (inputs are |x| <~ 32 here)
__device__ __forceinline__ float exp2_raw(float x) {
    float r;
    asm("v_exp_f32 %0, %1" : "=v"(r) : "v"(x));
    return r;
}

// LDS chunk swizzle for attn (measured 0 conflicts, r5)
#define SWZF(row, chunk) (((chunk) ^ ((row) & 7) ^ (((row) >> 3) & 3)))

// ---------------------------------------------------------------------------
// Convert X f32 -> bf16 (8M elems, 8 per thread)
// ---------------------------------------------------------------------------
__global__ __launch_bounds__(256) void conv_x(
    const float* __restrict__ X, unsigned short* __restrict__ Xb)
{
    const size_t i = (size_t)blockIdx.x * 256 + threadIdx.x;
    const float4* p = reinterpret_cast<const float4*>(X) + i * 2;
    float4 a = p[0], b = p[1];
    unsigned short r[8];
    r[0] = f2bf(a.x); r[1] = f2bf(a.y); r[2] = f2bf(a.z); r[3] = f2bf(a.w);
    r[4] = f2bf(b.x); r[5] = f2bf(b.y); r[6] = f2bf(b.z); r[7] = f2bf(b.w);
    *reinterpret_cast<uint4*>(Xb + i * 8) = *reinterpret_cast<const uint4*>(r);
}

// ---------------------------------------------------------------------------
// Transpose+convert W's: Wtb[proj*1024 + n][k] = W_proj[k][n] as bf16.
// Wq is pre-scaled by QSCALE (softmax scale * log2e) in f32 — free at runtime.
// ---------------------------------------------------------------------------
__global__ __launch_bounds__(256) void conv_w(
    const float* __restrict__ Wq, const float* __restrict__ Wk,
    const float* __restrict__ Wv, unsigned short* __restrict__ Wtb)
{
    const int proj = blockIdx.z;
    const float* W = (proj == 0) ? Wq : (proj == 1) ? Wk : Wv;
    const float sc = (proj == 0) ? QSCALE : 1.0f;
    __shared__ float tile[32][33];
    const int n0 = blockIdx.x * 32, k0 = blockIdx.y * 32;
    const int tx = threadIdx.x & 31, ty = threadIdx.x >> 5;  // 32 x 8
#pragma unroll
    for (int i = 0; i < 4; ++i)
        tile[ty + i * 8][tx] = W[(size_t)(k0 + ty + i * 8) * PE + n0 + tx];
    __syncthreads();
#pragma unroll
    for (int i = 0; i < 4; ++i)
        Wtb[(size_t)(proj * 1024 + n0 + ty + i * 8) * 1024 + k0 + tx] =
            f2bf(tile[tx][ty + i * 8] * sc);
}

// ---------------------------------------------------------------------------
// rel f32 -> bf16 table (2047 x 16)
// ---------------------------------------------------------------------------
__global__ __launch_bounds__(256) void conv_rel(
    const float* __restrict__ rel, unsigned short* __restrict__ relbf)
{
    const int i = blockIdx.x * 1024 + threadIdx.x * 4;
#pragma unroll
    for (int k = 0; k < 4; ++k)
        if (i + k < (2 * PS - 1) * PH) relbf[i + k] = f2bf(rel[i + k]);
}

// ---------------------------------------------------------------------------
// QKV GEMM: C[8192][3072] bf16 = Xb[8192][1024] @ Wtb^T, MFMA 16x16x32 bf16.
// m201-style phase-interleaved schedule at BM=256, BN=128, BK=64:
//   8 waves (2M x 4N), per-wave output 128x32, acc 8x2 frags (64 VGPR).
//   Per K-tile 2 phases: {<=12 ds_reads | stage | barrier | lgkm0 | 16 MFMA |
//   [vmcnt(6)] | barrier}.  Counted vmcnt, never 0 mid-loop (T3/T4).
//   Stage targets are dead LDS regions (B read in ph0; A staged in ph1).
// 768 blocks = exactly 3 rounds of 1 block/CU (96KB LDS) — no grid tail.
// ---------------------------------------------------------------------------
__global__ __launch_bounds__(512, 2) void qkv_mfma(
    const unsigned short* __restrict__ Xb,
    const unsigned short* __restrict__ Wtb,
    unsigned short* __restrict__ QKV)
{
    // 768 blocks = 8 XCD-chunks of 96; bijective (768 % 8 == 0)
    const int orig = blockIdx.x;
    const int wg = (orig & 7) * 96 + (orig >> 3);
    const int nblk = wg % 24, mblk = wg / 24;   // 24 n-tiles x 32 m-tiles
    const int m0 = mblk * 256, n0 = nblk * 128;

    __shared__ __align__(16) unsigned short As[2][256 * 64];  // 64 KB
    __shared__ __align__(16) unsigned short Bs[2][128 * 64];  // 32 KB

    const int t = threadIdx.x;              // 0..511
    const int l = t & 63, w = t >> 6;       // 8 waves
    const int lane15 = l & 15, lhi = l >> 4;
    const int wm = w >> 2, wn = w & 3;      // 2 x 4 wave grid

    f32x4 acc[8][2] = {};                   // 64 VGPR accumulator

    // A-half h (rows h*128..h*128+127) of K-tile kt -> buf c: 2 loads/thread
#define QSTAGE_AH(kt, c, h)                                                     \
    {                                                                           \
        _Pragma("unroll")                                                       \
        for (int rr = 0; rr < 2; ++rr) {                                        \
            const int ci = (h) * 1024 + rr * 512 + t;                           \
            const int r = ci >> 3;                                              \
            const int scl = (ci & 7) ^ (r & 7);                                 \
            gload_lds16(Xb + (size_t)(m0 + r) * 1024 + (kt) * 64 + scl * 8,     \
                        &As[c][ci * 8]);                                        \
        }                                                                       \
    }
    // B tile (128 rows) of K-tile kt -> buf c: 2 loads/thread
#define QSTAGE_B(kt, c)                                                         \
    {                                                                           \
        _Pragma("unroll")                                                       \
        for (int rr = 0; rr < 2; ++rr) {                                        \
            const int ci = rr * 512 + t;                                        \
            const int r = ci >> 3;                                              \
            const int scl = (ci & 7) ^ (r & 7);                                 \
            gload_lds16(Wtb + (size_t)(n0 + r) * 1024 + (kt) * 64 + scl * 8,    \
                        &Bs[c][ci * 8]);                                        \
        }                                                                       \
    }

    // prologue: tiles 0 and 1 fully staged (12 loads/thread in flight)
    QSTAGE_B(0, 0) QSTAGE_AH(0, 0, 0) QSTAGE_AH(0, 0, 1)
    QSTAGE_B(1, 1) QSTAGE_AH(1, 1, 0) QSTAGE_AH(1, 1, 1)
    asm volatile("s_waitcnt vmcnt(6)" ::: "memory");   // tile 0 landed
    __builtin_amdgcn_sched_barrier(0);
    __builtin_amdgcn_s_barrier();

    for (int kt = 0; kt < 16; ++kt) {
        const int c = kt & 1;
        bf16x8 afr[8][2], bfr[2][2];

        // ---- phase 0: read A[mi0-3] (8) + B[ni0-1] (4); MFMA low quadrants ----
#pragma unroll
        for (int mi = 0; mi < 4; ++mi)
#pragma unroll
            for (int kk = 0; kk < 2; ++kk) {
                const int row = wm * 128 + mi * 16 + lane15;
                afr[mi][kk] = *reinterpret_cast<const bf16x8*>(
                    &As[c][row * 64 + (((kk * 4 + lhi) ^ (row & 7)) << 3)]);
            }
#pragma unroll
        for (int ni = 0; ni < 2; ++ni)
#pragma unroll
            for (int kk = 0; kk < 2; ++kk) {
                const int row = wn * 32 + ni * 16 + lane15;
                bfr[ni][kk] = *reinterpret_cast<const bf16x8*>(
                    &Bs[c][row * 64 + (((kk * 4 + lhi) ^ (row & 7)) << 3)]);
            }
        asm volatile("s_waitcnt lgkmcnt(8)" ::: "memory");
        __builtin_amdgcn_s_barrier();
        asm volatile("s_waitcnt lgkmcnt(0)" ::: "memory");
        __builtin_amdgcn_sched_barrier(0);
        __builtin_amdgcn_s_setprio(1);
#pragma unroll
        for (int mi = 0; mi < 4; ++mi)
#pragma unroll
            for (int ni = 0; ni < 2; ++ni)
#pragma unroll
                for (int kk = 0; kk < 2; ++kk)
                    acc[mi][ni] = __builtin_amdgcn_mfma_f32_16x16x32_bf16(
                        afr[mi][kk], bfr[ni][kk], acc[mi][ni], 0, 0, 0);
        __builtin_amdgcn_s_setprio(0);
        __builtin_amdgcn_sched_barrier(0);
        __builtin_amdgcn_s_barrier();

        // ---- phase 1: read A[mi4-7] (8); stage tile kt+2 (6); MFMA high ----
#pragma unroll
        for (int mi = 4; mi < 8; ++mi)
#pragma unroll
            for (int kk = 0; kk < 2; ++kk) {
                const int row = wm * 128 + mi * 16 + lane15;
                afr[mi][kk] = *reinterpret_cast<const bf16x8*>(
                    &As[c][row * 64 + (((kk * 4 + lhi) ^ (row & 7)) << 3)]);
            }
        if (kt < 14) {
            // overwrites buf c regions already fully consumed (B: ph0; A: above)
            QSTAGE_B(kt + 2, c)
            QSTAGE_AH(kt + 2, c, 0)
            QSTAGE_AH(kt + 2, c, 1)
        }
        __builtin_amdgcn_s_barrier();
        asm volatile("s_waitcnt lgkmcnt(0)" ::: "memory");
        __builtin_amdgcn_sched_barrier(0);
        __builtin_amdgcn_s_setprio(1);
#pragma unroll
        for (int mi = 4; mi < 8; ++mi)
#pragma unroll
            for (int ni = 0; ni < 2; ++ni)
#pragma unroll
                for (int kk = 0; kk < 2; ++kk)
                    acc[mi][ni] = __builtin_amdgcn_mfma_f32_16x16x32_bf16(
                        afr[mi][kk], bfr[ni][kk], acc[mi][ni], 0, 0, 0);
        __builtin_amdgcn_s_setprio(0);
        __builtin_amdgcn_sched_barrier(0);
        if (kt < 14) {
            asm volatile("s_waitcnt vmcnt(6)" ::: "memory");   // tile kt+1 landed
        } else if (kt == 14) {
            asm volatile("s_waitcnt vmcnt(0)" ::: "memory");   // tile 15 landed
        }
        __builtin_amdgcn_sched_barrier(0);
        __builtin_amdgcn_s_barrier();
    }
#undef QSTAGE_AH
#undef QSTAGE_B

#pragma unroll
    for (int mi = 0; mi < 8; ++mi)
#pragma unroll
        for (int ni = 0; ni < 2; ++ni)
#pragma unroll
            for (int r = 0; r < 4; ++r) {
                const int gr = m0 + wm * 128 + mi * 16 + lhi * 4 + r;
                const int gc = n0 + wn * 32 + ni * 16 + lane15;
                QKV[(size_t)gr * 3072 + gc] = f2bf(acc[mi][ni][r]);
            }
}

// ---------------------------------------------------------------------------
// V transpose: VT[h][b][d][j] = QKV[b*S+j][2048 + h*64 + d]  (bf16, 16 MB)
// ---------------------------------------------------------------------------
__global__ __launch_bounds__(256) void vtrans(
    const unsigned short* __restrict__ QKV, unsigned short* __restrict__ VT)
{
    const int j0 = blockIdx.x * 64, b = blockIdx.y, h = blockIdx.z;
    __shared__ unsigned short tile[64][72];
    const int t = threadIdx.x;

#pragma unroll
    for (int it = 0; it < 2; ++it) {
        const int jr = it * 32 + (t >> 3), dc = t & 7;
        uint4 d = *reinterpret_cast<const uint4*>(
            QKV + ((size_t)(b * PS + j0 + jr)) * 3072 + 2048 + h * 64 + dc * 8);
        *reinterpret_cast<uint4*>(&tile[jr][dc * 8]) = d;
    }
    __syncthreads();
    const int d = t & 63, jc = t >> 6;
    unsigned short out[16];
#pragma unroll
    for (int k = 0; k < 16; ++k) out[k] = tile[jc * 16 + k][d];
    unsigned short* dst = VT + ((size_t)((h * 8 + b) * 64 + d)) * 1024 + j0 + jc * 16;
    *reinterpret_cast<uint4*>(dst)     = *reinterpret_cast<const uint4*>(out);
    *reinterpret_cast<uint4*>(dst + 8) = *reinterpret_cast<const uint4*>(out + 8);
}

// ---------------------------------------------------------------------------
// Fused attention, 32x32x16 MFMA, swapped QK^T, in-register softmax (T12),
// fused bias.V, row-sum via ones-MFMA.  Block = 4 waves x 32 q = 128 q-rows.
// sm-split tile body; raw v_exp_f32 (Q pre-scaled).  (r8: 74 us, conflicts 0)
// ---------------------------------------------------------------------------
__global__ __launch_bounds__(256) void attn_mfma(
    const unsigned short* __restrict__ qkv,
    const unsigned short* __restrict__ VT,
    const unsigned short* __restrict__ relbf,
    float* __restrict__ O)
{
    __shared__ __align__(16) unsigned short Ks[2][64 * 64];  // [j][d] swizzled
    __shared__ __align__(16) unsigned short Vt[2][64 * 64];  // [d][j] swizzled

    const int orig = blockIdx.x;                   // 1024 blocks
    const int wg = (orig & 7) * 128 + (orig >> 3); // XCD-chunked, bijective
    const int qt = wg & 7;
    const int h  = (wg >> 3) & 15;
    const int b  = wg >> 7;

    const int t = threadIdx.x;
    const int w = t >> 6, l = t & 63;
    const int lane31 = l & 31, hi = l >> 5;

    const int qrow_g = qt * 128 + w * 32 + lane31;   // query index i (0..1023)

    // Q fragments (B-operand of swapped QK): col=q=lane31, k=hi*8+e
    bf16x8 qf[4];
    {
        const unsigned short* qp =
            qkv + ((size_t)(b * PS) + qrow_g) * 3072 + h * 64 + hi * 8;
#pragma unroll
        for (int dw = 0; dw < 4; ++dw)
            qf[dw] = *reinterpret_cast<const bf16x8*>(qp + dw * 16);
    }

    const unsigned short* Kg = qkv + (size_t)(b * PS) * 3072 + 1024 + h * 64;
    const unsigned short* Vg = VT + ((size_t)((h * 8 + b) * 64)) * 1024;

    // hoisted bias-table pointer: af[jw] at tile tt = relp + tt*64 + jw*16
    const int s1 = (h << 6) | (qrow_g >> 4);
    const int s2hi = (qrow_g & 15) << 6;
    const unsigned short* relp = relbf + (size_t)(s2hi - s1 + PS - 1) * PH + hi * 8;

    f32x16 accP[2] = {};
    f32x16 accB[2] = {};
    f32x16 accL = {};
    bf16x8 ones;
#pragma unroll
    for (int i = 0; i < 8; ++i) ones[i] = (short)0x3F80;  // bf16 1.0

#define ATTN_STAGE(buf, j0)                                                          \
    {                                                                                \
        _Pragma("unroll")                                                            \
        for (int it = 0; it < 2; ++it) {                                             \
            const int ci = it * 256 + t;                                             \
            const int r = ci >> 3;                                                   \
            const int scl = SWZF(r, ci & 7);                                         \
            gload_lds16(Kg + (size_t)((j0) + r) * 3072 + scl * 8, &Ks[buf][ci * 8]); \
            gload_lds16(Vg + (size_t)r * 1024 + (j0) + scl * 8, &Vt[buf][ci * 8]);   \
        }                                                                            \
    }

    // softmax-finish for one 32-j half: sc -> two bf16x8 P fragments
#define SM_FINISH(sc, pfA, pfB)                                                      \
    {                                                                                \
        float p[16];                                                                 \
        _Pragma("unroll")                                                            \
        for (int r = 0; r < 16; ++r) p[r] = exp2_raw((sc)[r]);                       \
        unsigned int a0 = cvtpk_bf16(p[0],  p[1]),  a1 = cvtpk_bf16(p[2],  p[3]);    \
        unsigned int b0 = cvtpk_bf16(p[4],  p[5]),  b1 = cvtpk_bf16(p[6],  p[7]);    \
        unsigned int c0 = cvtpk_bf16(p[8],  p[9]),  c1 = cvtpk_bf16(p[10], p[11]);   \
        unsigned int d0 = cvtpk_bf16(p[12], p[13]), d1 = cvtpk_bf16(p[14], p[15]);   \
        plswap(a0, b0); plswap(a1, b1);                                              \
        plswap(c0, d0); plswap(c1, d1);                                              \
        union { unsigned int u[4]; bf16x8 v; } pk0, pk1;                             \
        pk0.u[0] = a0; pk0.u[1] = a1; pk0.u[2] = b0; pk0.u[3] = b1;                  \
        pk1.u[0] = c0; pk1.u[1] = c1; pk1.u[2] = d0; pk1.u[3] = d1;                  \
        (pfA) = pk0.v; (pfB) = pk1.v;                                                \
    }

    // PV + bias.V + row-sum for one 16-j slot jw with P fragment pf
#define PV_STEP(jw, pf)                                                              \
    {                                                                                \
        accL = __builtin_amdgcn_mfma_f32_32x32x16_bf16((pf), ones, accL, 0, 0, 0);   \
        _Pragma("unroll")                                                            \
        for (int dt = 0; dt < 2; ++dt) {                                             \
            const int row = dt * 32 + lane31;                                        \
            bf16x8 bV = *reinterpret_cast<const bf16x8*>(                            \
                &Vt[cur][row * 64 + (SWZF(row, (jw) * 2 + hi) << 3)]);               \
            accP[dt] = __builtin_amdgcn_mfma_f32_32x32x16_bf16(                      \
                (pf), bV, accP[dt], 0, 0, 0);                                        \
            accB[dt] = __builtin_amdgcn_mfma_f32_32x32x16_bf16(                      \
                af[jw], bV, accB[dt], 0, 0, 0);                                      \
        }                                                                            \
    }

    ATTN_STAGE(0, 0)

    for (int tt = 0; tt < 16; ++tt) {
        const int cur = tt & 1;
        const int j0 = tt * 64;

        // bias A-frags: 16 contiguous bf16 from relbf (L2-resident)
        bf16x8 af[4];
        __builtin_amdgcn_sched_barrier(0);
#pragma unroll
        for (int jw = 0; jw < 4; ++jw)
            af[jw] = *reinterpret_cast<const bf16x8*>(relp + j0 + jw * 16);
        __builtin_amdgcn_sched_barrier(0);
        if (tt < 15) {
            ATTN_STAGE(cur ^ 1, j0 + 64)
            __builtin_amdgcn_sched_barrier(0);
            asm volatile("s_waitcnt vmcnt(8)" ::: "memory");  // cur tile staged
        } else {
            asm volatile("s_waitcnt vmcnt(4)" ::: "memory");
        }
        __builtin_amdgcn_sched_barrier(0);
        __builtin_amdgcn_s_barrier();
        __builtin_amdgcn_sched_barrier(0);

        // --- QK^T both halves (8 MFMAs issued back-to-back) ---
        f32x16 sc0 = {}, sc1 = {};
        __builtin_amdgcn_s_setprio(1);
#pragma unroll
        for (int dw = 0; dw < 4; ++dw) {
            const int row = lane31;
            bf16x8 aK = *reinterpret_cast<const bf16x8*>(
                &Ks[cur][row * 64 + (SWZF(row, dw * 2 + hi) << 3)]);
            sc0 = __builtin_amdgcn_mfma_f32_32x32x16_bf16(aK, qf[dw], sc0, 0, 0, 0);
        }
#pragma unroll
        for (int dw = 0; dw < 4; ++dw) {
            const int row = 32 + lane31;
            bf16x8 aK = *reinterpret_cast<const bf16x8*>(
                &Ks[cur][row * 64 + (SWZF(row, dw * 2 + hi) << 3)]);
            sc1 = __builtin_amdgcn_mfma_f32_32x32x16_bf16(aK, qf[dw], sc1, 0, 0, 0);
        }
        __builtin_amdgcn_s_setprio(0);

        // --- SM0 (VALU; overlaps QK1 MFMA execution) ---
        bf16x8 pf0, pf1, pf2, pf3;
        SM_FINISH(sc0, pf0, pf1)

        // --- PV first half ---
        __builtin_amdgcn_s_setprio(1);
        PV_STEP(0, pf0)
        PV_STEP(1, pf1)
        __builtin_amdgcn_s_setprio(0);

        // --- SM1 (VALU; overlaps PV MFMA execution) ---
        SM_FINISH(sc1, pf2, pf3)

        // --- PV second half ---
        __builtin_amdgcn_s_setprio(1);
        PV_STEP(2, pf2)
        PV_STEP(3, pf3)
        __builtin_amdgcn_s_setprio(0);

        __builtin_amdgcn_s_barrier();
    }
#undef ATTN_STAGE
#undef SM_FINISH
#undef PV_STEP

    // accL[r] = l[q-row rl] replicated across all lanes of the row's quads
#pragma unroll
    for (int dt = 0; dt < 2; ++dt)
#pragma unroll
        for (int r = 0; r < 16; ++r) {
            const int rl = (r & 3) + 8 * (r >> 2) + 4 * hi;   // q-row local
            O[((size_t)(b * PS + qt * 128 + w * 32 + rl)) * PE + h * 64 + dt * 32 + lane31]
                = accP[dt][r] / accL[r] + accB[dt][r];
        }
}

// ---------------------------------------------------------------------------
// LayerNorm over last dim (1024), in-place on d_out.
// ---------------------------------------------------------------------------
__global__ __launch_bounds__(256) void layernorm_inplace(
    float* __restrict__ O,
    const float* __restrict__ gamma,
    const float* __restrict__ beta)
{
    const int row = blockIdx.x;
    float* p = O + (size_t)row * PE;
    const int t = threadIdx.x;

    float4 x = reinterpret_cast<float4*>(p)[t];
    float s  = x.x + x.y + x.z + x.w;
    float s2 = x.x * x.x + x.y * x.y + x.z * x.z + x.w * x.w;

#pragma unroll
    for (int off = 1; off < 64; off <<= 1) {
        s  += __shfl_xor(s, off, 64);
        s2 += __shfl_xor(s2, off, 64);
    }
    __shared__ float red[2][4];
    const int wid = t >> 6;
    if ((t & 63) == 0) { red[0][wid] = s; red[1][wid] = s2; }
    __syncthreads();
    const float ts  = red[0][0] + red[0][1] + red[0][2] + red[0][3];
    const float ts2 = red[1][0] + red[1][1] + red[1][2] + red[1][3];

    const float mu  = ts * (1.f / PE);
    const float var = ts2 * (1.f / PE) - mu * mu;
    const float inv = rsqrtf(var + EPSLN);

    const float4 g  = reinterpret_cast<const float4*>(gamma)[t];
    const float4 bb = reinterpret_cast<const float4*>(beta)[t];
    float4 y;
    y.x = (x.x - mu) * inv * g.x + bb.x;
    y.y = (x.y - mu) * inv * g.y + bb.y;
    y.z = (x.z - mu) * inv * g.z + bb.z;
    y.w = (x.w - mu) * inv * g.w + bb.w;
    reinterpret_cast<float4*>(p)[t] = y;
}

// ---------------------------------------------------------------------------
extern "C" void kernel_launch(void* const* d_in, const int* in_sizes, int n_in,
                              void* d_out, int out_size, void* d_ws, size_t ws_size,
                              hipStream_t stream) {
    (void)in_sizes; (void)n_in; (void)out_size; (void)ws_size;
    const float* x     = (const float*)d_in[0];
    const float* Wq    = (const float*)d_in[1];
    const float* Wk    = (const float*)d_in[2];
    const float* Wv    = (const float*)d_in[3];
    const float* rel   = (const float*)d_in[4];
    const float* gamma = (const float*)d_in[5];
    const float* beta  = (const float*)d_in[6];
    float* out = (float*)d_out;

    char* ws = (char*)d_ws;
    // Layout (86 MB): [Xb 16MB | Wtb 6MB | QKV 48MB | VT 16MB]
    // relbf (64KB) aliases Xb region: Xb dead after qkv_mfma; conv_rel runs after.
    unsigned short* Xb    = (unsigned short*)ws;
    unsigned short* Wtb   = (unsigned short*)(ws + 16777216);
    unsigned short* QKV   = (unsigned short*)(ws + 23068672);
    unsigned short* VT    = (unsigned short*)(ws + 73400320);
    unsigned short* relbf = (unsigned short*)ws;

    conv_x<<<4096, 256, 0, stream>>>(x, Xb);
    conv_w<<<dim3(32, 32, 3), 256, 0, stream>>>(Wq, Wk, Wv, Wtb);
    qkv_mfma<<<768, 512, 0, stream>>>(Xb, Wtb, QKV);
    conv_rel<<<32, 256, 0, stream>>>(rel, relbf);
    vtrans<<<dim3(16, 8, 16), 256, 0, stream>>>(QKV, VT);
    attn_mfma<<<1024, 256, 0, stream>>>(QKV, VT, relbf, out);
    layernorm_inplace<<<PB * PS, 256, 0, stream>>>(out, gamma, beta);
}

// Round 10
// 165.940 us; speedup vs baseline: 1.0499x; 1.0499x over previous
//
#include <hip/hip_runtime.h>
#include <hip/hip_bf16.h>

// Problem constants: B=8, S=1024, E=1024, H=16, D=64
#define PB 8
#define PS 1024
#define PE 1024
#define PH 16
#define PD 64
#define EPSLN 1e-3f
// softmax scale folded into Wq: SCALE * log2(e), so P = 2^s via raw v_exp_f32
#define QSCALE 0.04508422f   // (1/32) * 1.4426950408889634

typedef __attribute__((ext_vector_type(8))) short bf16x8;    // 8 bf16 = 4 VGPR
typedef __attribute__((ext_vector_type(4))) float f32x4;
typedef __attribute__((ext_vector_type(16))) float f32x16;

__device__ __forceinline__ unsigned short f2bf(float f) {
    unsigned int u = __float_as_uint(f);
    u += 0x7FFFu + ((u >> 16) & 1u);   // RNE
    return (unsigned short)(u >> 16);
}

__device__ __forceinline__ void gload_lds16(const void* g, void* l) {
    __builtin_amdgcn_global_load_lds(
        (const __attribute__((address_space(1))) unsigned int*)g,
        (__attribute__((address_space(3))) unsigned int*)l,
        16, 0, 0);
}

__device__ __forceinline__ unsigned int cvtpk_bf16(float lo, float hi) {
    unsigned int r;
    asm("v_cvt_pk_bf16_f32 %0, %1, %2" : "=v"(r) : "v"(lo), "v"(hi));
    return r;
}

__device__ __forceinline__ void plswap(unsigned int& a, unsigned int& b) {
    asm("v_permlane32_swap_b32 %0, %1" : "+v"(a), "+v"(b));
}

// raw hardware 2^x — no OCML denormal fix-up (inputs are |x| <~ 32 here)
__device__ __forceinline__ float exp2_raw(float x) {
    float r;
    asm("v_exp_f32 %0, %1" : "=v"(r) : "v"(x));
    return r;
}

// LDS chunk swizzle for attn (measured 0 conflicts, r5)
#define SWZF(row, chunk) (((chunk) ^ ((row) & 7) ^ (((row) >> 3) & 3)))

// ---------------------------------------------------------------------------
// Fused input conversion, one dispatch:
//   blocks [0,4096):     X f32 -> bf16 (8 elems/thread)
//   blocks [4096,7168):  W transpose+convert, Wtb[proj*1024+n][k] = W[k][n];
//                        Wq pre-scaled by QSCALE (f32, free).
// ---------------------------------------------------------------------------
__global__ __launch_bounds__(256) void conv_xw(
    const float* __restrict__ X,
    const float* __restrict__ Wq, const float* __restrict__ Wk,
    const float* __restrict__ Wv,
    unsigned short* __restrict__ Xb, unsigned short* __restrict__ Wtb)
{
    const int bx = blockIdx.x;
    if (bx < 4096) {
        const size_t i = (size_t)bx * 256 + threadIdx.x;
        const float4* p = reinterpret_cast<const float4*>(X) + i * 2;
        float4 a = p[0], b = p[1];
        unsigned short r[8];
        r[0] = f2bf(a.x); r[1] = f2bf(a.y); r[2] = f2bf(a.z); r[3] = f2bf(a.w);
        r[4] = f2bf(b.x); r[5] = f2bf(b.y); r[6] = f2bf(b.z); r[7] = f2bf(b.w);
        *reinterpret_cast<uint4*>(Xb + i * 8) = *reinterpret_cast<const uint4*>(r);
    } else {
        __shared__ float tile[32][33];
        const int wb = bx - 4096;             // 0..3071
        const int proj = wb >> 10;            // 0..2
        const int rem = wb & 1023;
        const float* W = (proj == 0) ? Wq : (proj == 1) ? Wk : Wv;
        const float sc = (proj == 0) ? QSCALE : 1.0f;
        const int n0 = (rem & 31) * 32, k0 = (rem >> 5) * 32;
        const int tx = threadIdx.x & 31, ty = threadIdx.x >> 5;  // 32 x 8
#pragma unroll
        for (int i = 0; i < 4; ++i)
            tile[ty + i * 8][tx] = W[(size_t)(k0 + ty + i * 8) * PE + n0 + tx];
        __syncthreads();
#pragma unroll
        for (int i = 0; i < 4; ++i)
            Wtb[(size_t)(proj * 1024 + n0 + ty + i * 8) * 1024 + k0 + tx] =
                f2bf(tile[tx][ty + i * 8] * sc);
    }
}

// ---------------------------------------------------------------------------
// rel f32 -> bf16 table (2047 x 16).  Runs after qkv (relbf aliases Xb).
// ---------------------------------------------------------------------------
__global__ __launch_bounds__(256) void conv_rel(
    const float* __restrict__ rel, unsigned short* __restrict__ relbf)
{
    const int i = blockIdx.x * 1024 + threadIdx.x * 4;
#pragma unroll
    for (int k = 0; k < 4; ++k)
        if (i + k < (2 * PS - 1) * PH) relbf[i + k] = f2bf(rel[i + k]);
}

// ---------------------------------------------------------------------------
// QKV GEMM: C[8192][3072] bf16 = Xb[8192][1024] @ Wtb^T, MFMA 16x16x32 bf16.
// m97 128x128 structure, 4 waves, 32KB LDS, ~3-4 blocks/CU — measured ~57us.
// FROZEN: two deep-pipeline ports (r6 256x256, r9 256x128 2-phase) both
// regressed to ~74-112us — 1 block/CU kills the inter-block overlap this
// structure gets for free at K=1024.
// ---------------------------------------------------------------------------
__global__ __launch_bounds__(256) void qkv_mfma(
    const unsigned short* __restrict__ Xb,
    const unsigned short* __restrict__ Wtb,
    unsigned short* __restrict__ QKV)
{
    const int orig = blockIdx.x;
    const int wg = (orig & 7) * 192 + (orig >> 3);
    const int nblk = wg % 24, mblk = wg / 24;
    const int m0 = mblk * 128, n0 = nblk * 128;

    __shared__ __align__(16) unsigned short As[128 * 64];
    __shared__ __align__(16) unsigned short Bs[128 * 64];

    const int t = threadIdx.x;
    const int w = t >> 6, l = t & 63;
    const int lane15 = l & 15, lhi = l >> 4;
    const int wm = w >> 1, wn = w & 1;

    f32x4 acc[4][4] = {};

    for (int k0 = 0; k0 < 1024; k0 += 64) {
        __syncthreads();
#pragma unroll
        for (int c = 0; c < 4; ++c) {
            const int ci = (w * 4 + c) * 64 + l;
            const int r = ci >> 3;
            const int srccl = (ci & 7) ^ (r & 7);
            gload_lds16(Xb  + (size_t)(m0 + r) * 1024 + k0 + srccl * 8, &As[ci * 8]);
            gload_lds16(Wtb + (size_t)(n0 + r) * 1024 + k0 + srccl * 8, &Bs[ci * 8]);
        }
        __syncthreads();
#pragma unroll
        for (int kk = 0; kk < 2; ++kk) {
            bf16x8 af[4], bf[4];
#pragma unroll
            for (int mi = 0; mi < 4; ++mi) {
                const int row = wm * 64 + mi * 16 + lane15;
                af[mi] = *reinterpret_cast<const bf16x8*>(
                    &As[row * 64 + (((kk * 4 + lhi) ^ (row & 7)) << 3)]);
            }
#pragma unroll
            for (int ni = 0; ni < 4; ++ni) {
                const int row = wn * 64 + ni * 16 + lane15;
                bf[ni] = *reinterpret_cast<const bf16x8*>(
                    &Bs[row * 64 + (((kk * 4 + lhi) ^ (row & 7)) << 3)]);
            }
#pragma unroll
            for (int mi = 0; mi < 4; ++mi)
#pragma unroll
                for (int ni = 0; ni < 4; ++ni)
                    acc[mi][ni] = __builtin_amdgcn_mfma_f32_16x16x32_bf16(
                        af[mi], bf[ni], acc[mi][ni], 0, 0, 0);
        }
    }
#pragma unroll
    for (int mi = 0; mi < 4; ++mi)
#pragma unroll
        for (int ni = 0; ni < 4; ++ni)
#pragma unroll
            for (int r = 0; r < 4; ++r) {
                const int gr = m0 + wm * 64 + mi * 16 + lhi * 4 + r;
                const int gc = n0 + wn * 64 + ni * 16 + lane15;
                QKV[(size_t)gr * 3072 + gc] = f2bf(acc[mi][ni][r]);
            }
}

// ---------------------------------------------------------------------------
// V transpose: VT[h][b][d][j] = QKV[b*S+j][2048 + h*64 + d]  (bf16, 16 MB)
// ---------------------------------------------------------------------------
__global__ __launch_bounds__(256) void vtrans(
    const unsigned short* __restrict__ QKV, unsigned short* __restrict__ VT)
{
    const int j0 = blockIdx.x * 64, b = blockIdx.y, h = blockIdx.z;
    __shared__ unsigned short tile[64][72];
    const int t = threadIdx.x;

#pragma unroll
    for (int it = 0; it < 2; ++it) {
        const int jr = it * 32 + (t >> 3), dc = t & 7;
        uint4 d = *reinterpret_cast<const uint4*>(
            QKV + ((size_t)(b * PS + j0 + jr)) * 3072 + 2048 + h * 64 + dc * 8);
        *reinterpret_cast<uint4*>(&tile[jr][dc * 8]) = d;
    }
    __syncthreads();
    const int d = t & 63, jc = t >> 6;
    unsigned short out[16];
#pragma unroll
    for (int k = 0; k < 16; ++k) out[k] = tile[jc * 16 + k][d];
    unsigned short* dst = VT + ((size_t)((h * 8 + b) * 64 + d)) * 1024 + j0 + jc * 16;
    *reinterpret_cast<uint4*>(dst)     = *reinterpret_cast<const uint4*>(out);
    *reinterpret_cast<uint4*>(dst + 8) = *reinterpret_cast<const uint4*>(out + 8);
}

// ---------------------------------------------------------------------------
// Fused attention, 32x32x16 MFMA, swapped QK^T, in-register softmax (T12),
// fused bias.V, row-sum via ones-MFMA.  Block = 4 waves x 32 q = 128 q-rows.
// sm-split tile body; raw v_exp_f32 (Q pre-scaled).  (r8: 74 us, conflicts 0)
// ---------------------------------------------------------------------------
__global__ __launch_bounds__(256) void attn_mfma(
    const unsigned short* __restrict__ qkv,
    const unsigned short* __restrict__ VT,
    const unsigned short* __restrict__ relbf,
    float* __restrict__ O)
{
    __shared__ __align__(16) unsigned short Ks[2][64 * 64];  // [j][d] swizzled
    __shared__ __align__(16) unsigned short Vt[2][64 * 64];  // [d][j] swizzled

    const int orig = blockIdx.x;                   // 1024 blocks
    const int wg = (orig & 7) * 128 + (orig >> 3); // XCD-chunked, bijective
    const int qt = wg & 7;
    const int h  = (wg >> 3) & 15;
    const int b  = wg >> 7;

    const int t = threadIdx.x;
    const int w = t >> 6, l = t & 63;
    const int lane31 = l & 31, hi = l >> 5;

    const int qrow_g = qt * 128 + w * 32 + lane31;   // query index i (0..1023)

    // Q fragments (B-operand of swapped QK): col=q=lane31, k=hi*8+e
    bf16x8 qf[4];
    {
        const unsigned short* qp =
            qkv + ((size_t)(b * PS) + qrow_g) * 3072 + h * 64 + hi * 8;
#pragma unroll
        for (int dw = 0; dw < 4; ++dw)
            qf[dw] = *reinterpret_cast<const bf16x8*>(qp + dw * 16);
    }

    const unsigned short* Kg = qkv + (size_t)(b * PS) * 3072 + 1024 + h * 64;
    const unsigned short* Vg = VT + ((size_t)((h * 8 + b) * 64)) * 1024;

    // hoisted bias-table pointer: af[jw] at tile tt = relp + tt*64 + jw*16
    const int s1 = (h << 6) | (qrow_g >> 4);
    const int s2hi = (qrow_g & 15) << 6;
    const unsigned short* relp = relbf + (size_t)(s2hi - s1 + PS - 1) * PH + hi * 8;

    f32x16 accP[2] = {};
    f32x16 accB[2] = {};
    f32x16 accL = {};
    bf16x8 ones;
#pragma unroll
    for (int i = 0; i < 8; ++i) ones[i] = (short)0x3F80;  // bf16 1.0

#define ATTN_STAGE(buf, j0)                                                          \
    {                                                                                \
        _Pragma("unroll")                                                            \
        for (int it = 0; it < 2; ++it) {                                             \
            const int ci = it * 256 + t;                                             \
            const int r = ci >> 3;                                                   \
            const int scl = SWZF(r, ci & 7);                                         \
            gload_lds16(Kg + (size_t)((j0) + r) * 3072 + scl * 8, &Ks[buf][ci * 8]); \
            gload_lds16(Vg + (size_t)r * 1024 + (j0) + scl * 8, &Vt[buf][ci * 8]);   \
        }                                                                            \
    }

    // softmax-finish for one 32-j half: sc -> two bf16x8 P fragments
#define SM_FINISH(sc, pfA, pfB)                                                      \
    {                                                                                \
        float p[16];                                                                 \
        _Pragma("unroll")                                                            \
        for (int r = 0; r < 16; ++r) p[r] = exp2_raw((sc)[r]);                       \
        unsigned int a0 = cvtpk_bf16(p[0],  p[1]),  a1 = cvtpk_bf16(p[2],  p[3]);    \
        unsigned int b0 = cvtpk_bf16(p[4],  p[5]),  b1 = cvtpk_bf16(p[6],  p[7]);    \
        unsigned int c0 = cvtpk_bf16(p[8],  p[9]),  c1 = cvtpk_bf16(p[10], p[11]);   \
        unsigned int d0 = cvtpk_bf16(p[12], p[13]), d1 = cvtpk_bf16(p[14], p[15]);   \
        plswap(a0, b0); plswap(a1, b1);                                              \
        plswap(c0, d0); plswap(c1, d1);                                              \
        union { unsigned int u[4]; bf16x8 v; } pk0, pk1;                             \
        pk0.u[0] = a0; pk0.u[1] = a1; pk0.u[2] = b0; pk0.u[3] = b1;                  \
        pk1.u[0] = c0; pk1.u[1] = c1; pk1.u[2] = d0; pk1.u[3] = d1;                  \
        (pfA) = pk0.v; (pfB) = pk1.v;                                                \
    }

    // PV + bias.V + row-sum for one 16-j slot jw with P fragment pf
#define PV_STEP(jw, pf)                                                              \
    {                                                                                \
        accL = __builtin_amdgcn_mfma_f32_32x32x16_bf16((pf), ones, accL, 0, 0, 0);   \
        _Pragma("unroll")                                                            \
        for (int dt = 0; dt < 2; ++dt) {                                             \
            const int row = dt * 32 + lane31;                                        \
            bf16x8 bV = *reinterpret_cast<const bf16x8*>(                            \
                &Vt[cur][row * 64 + (SWZF(row, (jw) * 2 + hi) << 3)]);               \
            accP[dt] = __builtin_amdgcn_mfma_f32_32x32x16_bf16(                      \
                (pf), bV, accP[dt], 0, 0, 0);                                        \
            accB[dt] = __builtin_amdgcn_mfma_f32_32x32x16_bf16(                      \
                af[jw], bV, accB[dt], 0, 0, 0);                                      \
        }                                                                            \
    }

    ATTN_STAGE(0, 0)

    for (int tt = 0; tt < 16; ++tt) {
        const int cur = tt & 1;
        const int j0 = tt * 64;

        // bias A-frags: 16 contiguous bf16 from relbf (L2-resident)
        bf16x8 af[4];
        __builtin_amdgcn_sched_barrier(0);
#pragma unroll
        for (int jw = 0; jw < 4; ++jw)
            af[jw] = *reinterpret_cast<const bf16x8*>(relp + j0 + jw * 16);
        __builtin_amdgcn_sched_barrier(0);
        if (tt < 15) {
            ATTN_STAGE(cur ^ 1, j0 + 64)
            __builtin_amdgcn_sched_barrier(0);
            asm volatile("s_waitcnt vmcnt(8)" ::: "memory");  // cur tile staged
        } else {
            asm volatile("s_waitcnt vmcnt(4)" ::: "memory");
        }
        __builtin_amdgcn_sched_barrier(0);
        __builtin_amdgcn_s_barrier();
        __builtin_amdgcn_sched_barrier(0);

        // --- QK^T both halves (8 MFMAs issued back-to-back) ---
        f32x16 sc0 = {}, sc1 = {};
        __builtin_amdgcn_s_setprio(1);
#pragma unroll
        for (int dw = 0; dw < 4; ++dw) {
            const int row = lane31;
            bf16x8 aK = *reinterpret_cast<const bf16x8*>(
                &Ks[cur][row * 64 + (SWZF(row, dw * 2 + hi) << 3)]);
            sc0 = __builtin_amdgcn_mfma_f32_32x32x16_bf16(aK, qf[dw], sc0, 0, 0, 0);
        }
#pragma unroll
        for (int dw = 0; dw < 4; ++dw) {
            const int row = 32 + lane31;
            bf16x8 aK = *reinterpret_cast<const bf16x8*>(
                &Ks[cur][row * 64 + (SWZF(row, dw * 2 + hi) << 3)]);
            sc1 = __builtin_amdgcn_mfma_f32_32x32x16_bf16(aK, qf[dw], sc1, 0, 0, 0);
        }
        __builtin_amdgcn_s_setprio(0);

        // --- SM0 (VALU; overlaps QK1 MFMA execution) ---
        bf16x8 pf0, pf1, pf2, pf3;
        SM_FINISH(sc0, pf0, pf1)

        // --- PV first half ---
        __builtin_amdgcn_s_setprio(1);
        PV_STEP(0, pf0)
        PV_STEP(1, pf1)
        __builtin_amdgcn_s_setprio(0);

        // --- SM1 (VALU; overlaps PV MFMA execution) ---
        SM_FINISH(sc1, pf2, pf3)

        // --- PV second half ---
        __builtin_amdgcn_s_setprio(1);
        PV_STEP(2, pf2)
        PV_STEP(3, pf3)
        __builtin_amdgcn_s_setprio(0);

        __builtin_amdgcn_s_barrier();
    }
#undef ATTN_STAGE
#undef SM_FINISH
#undef PV_STEP

    // accL[r] = l[q-row rl] replicated across all lanes of the row's quads
#pragma unroll
    for (int dt = 0; dt < 2; ++dt)
#pragma unroll
        for (int r = 0; r < 16; ++r) {
            const int rl = (r & 3) + 8 * (r >> 2) + 4 * hi;   // q-row local
            O[((size_t)(b * PS + qt * 128 + w * 32 + rl)) * PE + h * 64 + dt * 32 + lane31]
                = accP[dt][r] / accL[r] + accB[dt][r];
        }
}

// ---------------------------------------------------------------------------
// LayerNorm over last dim (1024), in-place on d_out.  (HBM-bound, ~11us)
// ---------------------------------------------------------------------------
__global__ __launch_bounds__(256) void layernorm_inplace(
    float* __restrict__ O,
    const float* __restrict__ gamma,
    const float* __restrict__ beta)
{
    const int row = blockIdx.x;
    float* p = O + (size_t)row * PE;
    const int t = threadIdx.x;

    float4 x = reinterpret_cast<float4*>(p)[t];
    float s  = x.x + x.y + x.z + x.w;
    float s2 = x.x * x.x + x.y * x.y + x.z * x.z + x.w * x.w;

#pragma unroll
    for (int off = 1; off < 64; off <<= 1) {
        s  += __shfl_xor(s, off, 64);
        s2 += __shfl_xor(s2, off, 64);
    }
    __shared__ float red[2][4];
    const int wid = t >> 6;
    if ((t & 63) == 0) { red[0][wid] = s; red[1][wid] = s2; }
    __syncthreads();
    const float ts  = red[0][0] + red[0][1] + red[0][2] + red[0][3];
    const float ts2 = red[1][0] + red[1][1] + red[1][2] + red[1][3];

    const float mu  = ts * (1.f / PE);
    const float var = ts2 * (1.f / PE) - mu * mu;
    const float inv = rsqrtf(var + EPSLN);

    const float4 g  = reinterpret_cast<const float4*>(gamma)[t];
    const float4 bb = reinterpret_cast<const float4*>(beta)[t];
    float4 y;
    y.x = (x.x - mu) * inv * g.x + bb.x;
    y.y = (x.y - mu) * inv * g.y + bb.y;
    y.z = (x.z - mu) * inv * g.z + bb.z;
    y.w = (x.w - mu) * inv * g.w + bb.w;
    reinterpret_cast<float4*>(p)[t] = y;
}

// ---------------------------------------------------------------------------
extern "C" void kernel_launch(void* const* d_in, const int* in_sizes, int n_in,
                              void* d_out, int out_size, void* d_ws, size_t ws_size,
                              hipStream_t stream) {
    (void)in_sizes; (void)n_in; (void)out_size; (void)ws_size;
    const float* x     = (const float*)d_in[0];
    const float* Wq    = (const float*)d_in[1];
    const float* Wk    = (const float*)d_in[2];
    const float* Wv    = (const float*)d_in[3];
    const float* rel   = (const float*)d_in[4];
    const float* gamma = (const float*)d_in[5];
    const float* beta  = (const float*)d_in[6];
    float* out = (float*)d_out;

    char* ws = (char*)d_ws;
    // Layout (86 MB): [Xb 16MB | Wtb 6MB | QKV 48MB | VT 16MB]
    // relbf (64KB) aliases Xb region: Xb dead after qkv_mfma; conv_rel runs after.
    unsigned short* Xb    = (unsigned short*)ws;
    unsigned short* Wtb   = (unsigned short*)(ws + 16777216);
    unsigned short* QKV   = (unsigned short*)(ws + 23068672);
    unsigned short* VT    = (unsigned short*)(ws + 73400320);
    unsigned short* relbf = (unsigned short*)ws;

    conv_xw<<<7168, 256, 0, stream>>>(x, Wq, Wk, Wv, Xb, Wtb);
    qkv_mfma<<<1536, 256, 0, stream>>>(Xb, Wtb, QKV);
    conv_rel<<<32, 256, 0, stream>>>(rel, relbf);
    vtrans<<<dim3(16, 8, 16), 256, 0, stream>>>(QKV, VT);
    attn_mfma<<<1024, 256, 0, stream>>>(QKV, VT, relbf, out);
    layernorm_inplace<<<PB * PS, 256, 0, stream>>>(out, gamma, beta);
}

// Round 11
// 162.350 us; speedup vs baseline: 1.0731x; 1.0221x over previous
//
#include <hip/hip_runtime.h>
#include <hip/hip_bf16.h>

// Problem constants: B=8, S=1024, E=1024, H=16, D=64
#define PB 8
#define PS 1024
#define PE 1024
#define PH 16
#define PD 64
#define EPSLN 1e-3f
// softmax scale folded into Wq: SCALE * log2(e), so P = 2^s via raw v_exp_f32
#define QSCALE 0.04508422f   // (1/32) * 1.4426950408889634

typedef __attribute__((ext_vector_type(8))) short bf16x8;    // 8 bf16 = 4 VGPR
typedef __attribute__((ext_vector_type(4))) float f32x4;
typedef __attribute__((ext_vector_type(16))) float f32x16;

__device__ __forceinline__ unsigned short f2bf(float f) {
    unsigned int u = __float_as_uint(f);
    u += 0x7FFFu + ((u >> 16) & 1u);   // RNE
    return (unsigned short)(u >> 16);
}

__device__ __forceinline__ void gload_lds16(const void* g, void* l) {
    __builtin_amdgcn_global_load_lds(
        (const __attribute__((address_space(1))) unsigned int*)g,
        (__attribute__((address_space(3))) unsigned int*)l,
        16, 0, 0);
}

__device__ __forceinline__ unsigned int cvtpk_bf16(float lo, float hi) {
    unsigned int r;
    asm("v_cvt_pk_bf16_f32 %0, %1, %2" : "=v"(r) : "v"(lo), "v"(hi));
    return r;
}

__device__ __forceinline__ void plswap(unsigned int& a, unsigned int& b) {
    asm("v_permlane32_swap_b32 %0, %1" : "+v"(a), "+v"(b));
}

// raw hardware 2^x — no OCML denormal fix-up (inputs are |x| <~ 32 here)
__device__ __forceinline__ float exp2_raw(float x) {
    float r;
    asm("v_exp_f32 %0, %1" : "=v"(r) : "v"(x));
    return r;
}

// LDS chunk swizzle for attn (measured 0 conflicts, r5)
#define SWZF(row, chunk) (((chunk) ^ ((row) & 7) ^ (((row) >> 3) & 3)))

// ---------------------------------------------------------------------------
// Fused input conversion, one dispatch:
//   blocks [0,4096):     X f32 -> bf16 (8 elems/thread)
//   blocks [4096,7168):  W transpose+convert, Wtb[proj*1024+n][k] = W[k][n];
//                        Wq pre-scaled by QSCALE (f32, free).
// ---------------------------------------------------------------------------
__global__ __launch_bounds__(256) void conv_xw(
    const float* __restrict__ X,
    const float* __restrict__ Wq, const float* __restrict__ Wk,
    const float* __restrict__ Wv,
    unsigned short* __restrict__ Xb, unsigned short* __restrict__ Wtb)
{
    const int bx = blockIdx.x;
    if (bx < 4096) {
        const size_t i = (size_t)bx * 256 + threadIdx.x;
        const float4* p = reinterpret_cast<const float4*>(X) + i * 2;
        float4 a = p[0], b = p[1];
        unsigned short r[8];
        r[0] = f2bf(a.x); r[1] = f2bf(a.y); r[2] = f2bf(a.z); r[3] = f2bf(a.w);
        r[4] = f2bf(b.x); r[5] = f2bf(b.y); r[6] = f2bf(b.z); r[7] = f2bf(b.w);
        *reinterpret_cast<uint4*>(Xb + i * 8) = *reinterpret_cast<const uint4*>(r);
    } else {
        __shared__ float tile[32][33];
        const int wb = bx - 4096;             // 0..3071
        const int proj = wb >> 10;            // 0..2
        const int rem = wb & 1023;
        const float* W = (proj == 0) ? Wq : (proj == 1) ? Wk : Wv;
        const float sc = (proj == 0) ? QSCALE : 1.0f;
        const int n0 = (rem & 31) * 32, k0 = (rem >> 5) * 32;
        const int tx = threadIdx.x & 31, ty = threadIdx.x >> 5;  // 32 x 8
#pragma unroll
        for (int i = 0; i < 4; ++i)
            tile[ty + i * 8][tx] = W[(size_t)(k0 + ty + i * 8) * PE + n0 + tx];
        __syncthreads();
#pragma unroll
        for (int i = 0; i < 4; ++i)
            Wtb[(size_t)(proj * 1024 + n0 + ty + i * 8) * 1024 + k0 + tx] =
                f2bf(tile[tx][ty + i * 8] * sc);
    }
}

// ---------------------------------------------------------------------------
// rel f32 -> bf16 table (2047 x 16).  Runs after qkv (relbf aliases Xb).
// ---------------------------------------------------------------------------
__global__ __launch_bounds__(256) void conv_rel(
    const float* __restrict__ rel, unsigned short* __restrict__ relbf)
{
    const int i = blockIdx.x * 1024 + threadIdx.x * 4;
#pragma unroll
    for (int k = 0; k < 4; ++k)
        if (i + k < (2 * PS - 1) * PH) relbf[i + k] = f2bf(rel[i + k]);
}

// ---------------------------------------------------------------------------
// QKV GEMM: MFMA 16x16x32 bf16, m97 128x128 structure (FROZEN, ~57us).
// Q/K thirds (n0 < 2048) write row-major into QKV.
// V third (n0 >= 2048) writes DIRECTLY in transposed VT[h][b][d][j] layout:
//   each thread's 4 acc rows are 4 consecutive j at fixed d -> one uint2
//   store.  This eliminates the separate vtrans kernel (32MB round-trip).
// ---------------------------------------------------------------------------
__global__ __launch_bounds__(256) void qkv_mfma(
    const unsigned short* __restrict__ Xb,
    const unsigned short* __restrict__ Wtb,
    unsigned short* __restrict__ QKV,
    unsigned short* __restrict__ VT)
{
    const int orig = blockIdx.x;
    const int wg = (orig & 7) * 192 + (orig >> 3);
    const int nblk = wg % 24, mblk = wg / 24;
    const int m0 = mblk * 128, n0 = nblk * 128;

    __shared__ __align__(16) unsigned short As[128 * 64];
    __shared__ __align__(16) unsigned short Bs[128 * 64];

    const int t = threadIdx.x;
    const int w = t >> 6, l = t & 63;
    const int lane15 = l & 15, lhi = l >> 4;
    const int wm = w >> 1, wn = w & 1;

    f32x4 acc[4][4] = {};

    for (int k0 = 0; k0 < 1024; k0 += 64) {
        __syncthreads();
#pragma unroll
        for (int c = 0; c < 4; ++c) {
            const int ci = (w * 4 + c) * 64 + l;
            const int r = ci >> 3;
            const int srccl = (ci & 7) ^ (r & 7);
            gload_lds16(Xb  + (size_t)(m0 + r) * 1024 + k0 + srccl * 8, &As[ci * 8]);
            gload_lds16(Wtb + (size_t)(n0 + r) * 1024 + k0 + srccl * 8, &Bs[ci * 8]);
        }
        __syncthreads();
#pragma unroll
        for (int kk = 0; kk < 2; ++kk) {
            bf16x8 af[4], bf[4];
#pragma unroll
            for (int mi = 0; mi < 4; ++mi) {
                const int row = wm * 64 + mi * 16 + lane15;
                af[mi] = *reinterpret_cast<const bf16x8*>(
                    &As[row * 64 + (((kk * 4 + lhi) ^ (row & 7)) << 3)]);
            }
#pragma unroll
            for (int ni = 0; ni < 4; ++ni) {
                const int row = wn * 64 + ni * 16 + lane15;
                bf[ni] = *reinterpret_cast<const bf16x8*>(
                    &Bs[row * 64 + (((kk * 4 + lhi) ^ (row & 7)) << 3)]);
            }
#pragma unroll
            for (int mi = 0; mi < 4; ++mi)
#pragma unroll
                for (int ni = 0; ni < 4; ++ni)
                    acc[mi][ni] = __builtin_amdgcn_mfma_f32_16x16x32_bf16(
                        af[mi], bf[ni], acc[mi][ni], 0, 0, 0);
        }
    }

    if (n0 < 2048) {
        // Q/K projections: row-major C-write into QKV
#pragma unroll
        for (int mi = 0; mi < 4; ++mi)
#pragma unroll
            for (int ni = 0; ni < 4; ++ni)
#pragma unroll
                for (int r = 0; r < 4; ++r) {
                    const int gr = m0 + wm * 64 + mi * 16 + lhi * 4 + r;
                    const int gc = n0 + wn * 64 + ni * 16 + lane15;
                    QKV[(size_t)gr * 3072 + gc] = f2bf(acc[mi][ni][r]);
                }
    } else {
        // V projection: direct transposed write VT[h][b][d][j], 8B per thread-frag
#pragma unroll
        for (int mi = 0; mi < 4; ++mi)
#pragma unroll
            for (int ni = 0; ni < 4; ++ni) {
                const int gcv = (n0 - 2048) + wn * 64 + ni * 16 + lane15;
                const int h = gcv >> 6, d = gcv & 63;
                const int gr = m0 + wm * 64 + mi * 16 + lhi * 4;  // j, j+1, j+2, j+3
                const int bb = gr >> 10, j = gr & 1023;
                unsigned short pk[4];
#pragma unroll
                for (int r = 0; r < 4; ++r) pk[r] = f2bf(acc[mi][ni][r]);
                *reinterpret_cast<uint2*>(
                    VT + ((size_t)((h * 8 + bb) * 64 + d)) * 1024 + j) =
                    *reinterpret_cast<const uint2*>(pk);
            }
    }
}

// ---------------------------------------------------------------------------
// Fused attention, 32x32x16 MFMA, swapped QK^T, in-register softmax (T12),
// fused bias.V, row-sum via ones-MFMA.  Block = 4 waves x 32 q = 128 q-rows.
// sm-split tile body; raw v_exp_f32 (Q pre-scaled).  (r8: 74 us, conflicts 0)
// ---------------------------------------------------------------------------
__global__ __launch_bounds__(256) void attn_mfma(
    const unsigned short* __restrict__ qkv,
    const unsigned short* __restrict__ VT,
    const unsigned short* __restrict__ relbf,
    float* __restrict__ O)
{
    __shared__ __align__(16) unsigned short Ks[2][64 * 64];  // [j][d] swizzled
    __shared__ __align__(16) unsigned short Vt[2][64 * 64];  // [d][j] swizzled

    const int orig = blockIdx.x;                   // 1024 blocks
    const int wg = (orig & 7) * 128 + (orig >> 3); // XCD-chunked, bijective
    const int qt = wg & 7;
    const int h  = (wg >> 3) & 15;
    const int b  = wg >> 7;

    const int t = threadIdx.x;
    const int w = t >> 6, l = t & 63;
    const int lane31 = l & 31, hi = l >> 5;

    const int qrow_g = qt * 128 + w * 32 + lane31;   // query index i (0..1023)

    // Q fragments (B-operand of swapped QK): col=q=lane31, k=hi*8+e
    bf16x8 qf[4];
    {
        const unsigned short* qp =
            qkv + ((size_t)(b * PS) + qrow_g) * 3072 + h * 64 + hi * 8;
#pragma unroll
        for (int dw = 0; dw < 4; ++dw)
            qf[dw] = *reinterpret_cast<const bf16x8*>(qp + dw * 16);
    }

    const unsigned short* Kg = qkv + (size_t)(b * PS) * 3072 + 1024 + h * 64;
    const unsigned short* Vg = VT + ((size_t)((h * 8 + b) * 64)) * 1024;

    // hoisted bias-table pointer: af[jw] at tile tt = relp + tt*64 + jw*16
    const int s1 = (h << 6) | (qrow_g >> 4);
    const int s2hi = (qrow_g & 15) << 6;
    const unsigned short* relp = relbf + (size_t)(s2hi - s1 + PS - 1) * PH + hi * 8;

    f32x16 accP[2] = {};
    f32x16 accB[2] = {};
    f32x16 accL = {};
    bf16x8 ones;
#pragma unroll
    for (int i = 0; i < 8; ++i) ones[i] = (short)0x3F80;  // bf16 1.0

#define ATTN_STAGE(buf, j0)                                                          \
    {                                                                                \
        _Pragma("unroll")                                                            \
        for (int it = 0; it < 2; ++it) {                                             \
            const int ci = it * 256 + t;                                             \
            const int r = ci >> 3;                                                   \
            const int scl = SWZF(r, ci & 7);                                         \
            gload_lds16(Kg + (size_t)((j0) + r) * 3072 + scl * 8, &Ks[buf][ci * 8]); \
            gload_lds16(Vg + (size_t)r * 1024 + (j0) + scl * 8, &Vt[buf][ci * 8]);   \
        }                                                                            \
    }

    // softmax-finish for one 32-j half: sc -> two bf16x8 P fragments
#define SM_FINISH(sc, pfA, pfB)                                                      \
    {                                                                                \
        float p[16];                                                                 \
        _Pragma("unroll")                                                            \
        for (int r = 0; r < 16; ++r) p[r] = exp2_raw((sc)[r]);                       \
        unsigned int a0 = cvtpk_bf16(p[0],  p[1]),  a1 = cvtpk_bf16(p[2],  p[3]);    \
        unsigned int b0 = cvtpk_bf16(p[4],  p[5]),  b1 = cvtpk_bf16(p[6],  p[7]);    \
        unsigned int c0 = cvtpk_bf16(p[8],  p[9]),  c1 = cvtpk_bf16(p[10], p[11]);   \
        unsigned int d0 = cvtpk_bf16(p[12], p[13]), d1 = cvtpk_bf16(p[14], p[15]);   \
        plswap(a0, b0); plswap(a1, b1);                                              \
        plswap(c0, d0); plswap(c1, d1);                                              \
        union { unsigned int u[4]; bf16x8 v; } pk0, pk1;                             \
        pk0.u[0] = a0; pk0.u[1] = a1; pk0.u[2] = b0; pk0.u[3] = b1;                  \
        pk1.u[0] = c0; pk1.u[1] = c1; pk1.u[2] = d0; pk1.u[3] = d1;                  \
        (pfA) = pk0.v; (pfB) = pk1.v;                                                \
    }

    // PV + bias.V + row-sum for one 16-j slot jw with P fragment pf
#define PV_STEP(jw, pf)                                                              \
    {                                                                                \
        accL = __builtin_amdgcn_mfma_f32_32x32x16_bf16((pf), ones, accL, 0, 0, 0);   \
        _Pragma("unroll")                                                            \
        for (int dt = 0; dt < 2; ++dt) {                                             \
            const int row = dt * 32 + lane31;                                        \
            bf16x8 bV = *reinterpret_cast<const bf16x8*>(                            \
                &Vt[cur][row * 64 + (SWZF(row, (jw) * 2 + hi) << 3)]);               \
            accP[dt] = __builtin_amdgcn_mfma_f32_32x32x16_bf16(                      \
                (pf), bV, accP[dt], 0, 0, 0);                                        \
            accB[dt] = __builtin_amdgcn_mfma_f32_32x32x16_bf16(                      \
                af[jw], bV, accB[dt], 0, 0, 0);                                      \
        }                                                                            \
    }

    ATTN_STAGE(0, 0)

    for (int tt = 0; tt < 16; ++tt) {
        const int cur = tt & 1;
        const int j0 = tt * 64;

        // bias A-frags: 16 contiguous bf16 from relbf (L2-resident)
        bf16x8 af[4];
        __builtin_amdgcn_sched_barrier(0);
#pragma unroll
        for (int jw = 0; jw < 4; ++jw)
            af[jw] = *reinterpret_cast<const bf16x8*>(relp + j0 + jw * 16);
        __builtin_amdgcn_sched_barrier(0);
        if (tt < 15) {
            ATTN_STAGE(cur ^ 1, j0 + 64)
            __builtin_amdgcn_sched_barrier(0);
            asm volatile("s_waitcnt vmcnt(8)" ::: "memory");  // cur tile staged
        } else {
            asm volatile("s_waitcnt vmcnt(4)" ::: "memory");
        }
        __builtin_amdgcn_sched_barrier(0);
        __builtin_amdgcn_s_barrier();
        __builtin_amdgcn_sched_barrier(0);

        // --- QK^T both halves (8 MFMAs issued back-to-back) ---
        f32x16 sc0 = {}, sc1 = {};
        __builtin_amdgcn_s_setprio(1);
#pragma unroll
        for (int dw = 0; dw < 4; ++dw) {
            const int row = lane31;
            bf16x8 aK = *reinterpret_cast<const bf16x8*>(
                &Ks[cur][row * 64 + (SWZF(row, dw * 2 + hi) << 3)]);
            sc0 = __builtin_amdgcn_mfma_f32_32x32x16_bf16(aK, qf[dw], sc0, 0, 0, 0);
        }
#pragma unroll
        for (int dw = 0; dw < 4; ++dw) {
            const int row = 32 + lane31;
            bf16x8 aK = *reinterpret_cast<const bf16x8*>(
                &Ks[cur][row * 64 + (SWZF(row, dw * 2 + hi) << 3)]);
            sc1 = __builtin_amdgcn_mfma_f32_32x32x16_bf16(aK, qf[dw], sc1, 0, 0, 0);
        }
        __builtin_amdgcn_s_setprio(0);

        // --- SM0 (VALU; overlaps QK1 MFMA execution) ---
        bf16x8 pf0, pf1, pf2, pf3;
        SM_FINISH(sc0, pf0, pf1)

        // --- PV first half ---
        __builtin_amdgcn_s_setprio(1);
        PV_STEP(0, pf0)
        PV_STEP(1, pf1)
        __builtin_amdgcn_s_setprio(0);

        // --- SM1 (VALU; overlaps PV MFMA execution) ---
        SM_FINISH(sc1, pf2, pf3)

        // --- PV second half ---
        __builtin_amdgcn_s_setprio(1);
        PV_STEP(2, pf2)
        PV_STEP(3, pf3)
        __builtin_amdgcn_s_setprio(0);

        __builtin_amdgcn_s_barrier();
    }
#undef ATTN_STAGE
#undef SM_FINISH
#undef PV_STEP

    // accL[r] = l[q-row rl] replicated across all lanes of the row's quads
#pragma unroll
    for (int dt = 0; dt < 2; ++dt)
#pragma unroll
        for (int r = 0; r < 16; ++r) {
            const int rl = (r & 3) + 8 * (r >> 2) + 4 * hi;   // q-row local
            O[((size_t)(b * PS + qt * 128 + w * 32 + rl)) * PE + h * 64 + dt * 32 + lane31]
                = accP[dt][r] / accL[r] + accB[dt][r];
        }
}

// ---------------------------------------------------------------------------
// LayerNorm over last dim (1024), in-place on d_out.  (HBM-bound, ~11us)
// ---------------------------------------------------------------------------
__global__ __launch_bounds__(256) void layernorm_inplace(
    float* __restrict__ O,
    const float* __restrict__ gamma,
    const float* __restrict__ beta)
{
    const int row = blockIdx.x;
    float* p = O + (size_t)row * PE;
    const int t = threadIdx.x;

    float4 x = reinterpret_cast<float4*>(p)[t];
    float s  = x.x + x.y + x.z + x.w;
    float s2 = x.x * x.x + x.y * x.y + x.z * x.z + x.w * x.w;

#pragma unroll
    for (int off = 1; off < 64; off <<= 1) {
        s  += __shfl_xor(s, off, 64);
        s2 += __shfl_xor(s2, off, 64);
    }
    __shared__ float red[2][4];
    const int wid = t >> 6;
    if ((t & 63) == 0) { red[0][wid] = s; red[1][wid] = s2; }
    __syncthreads();
    const float ts  = red[0][0] + red[0][1] + red[0][2] + red[0][3];
    const float ts2 = red[1][0] + red[1][1] + red[1][2] + red[1][3];

    const float mu  = ts * (1.f / PE);
    const float var = ts2 * (1.f / PE) - mu * mu;
    const float inv = rsqrtf(var + EPSLN);

    const float4 g  = reinterpret_cast<const float4*>(gamma)[t];
    const float4 bb = reinterpret_cast<const float4*>(beta)[t];
    float4 y;
    y.x = (x.x - mu) * inv * g.x + bb.x;
    y.y = (x.y - mu) * inv * g.y + bb.y;
    y.z = (x.z - mu) * inv * g.z + bb.z;
    y.w = (x.w - mu) * inv * g.w + bb.w;
    reinterpret_cast<float4*>(p)[t] = y;
}

// ---------------------------------------------------------------------------
extern "C" void kernel_launch(void* const* d_in, const int* in_sizes, int n_in,
                              void* d_out, int out_size, void* d_ws, size_t ws_size,
                              hipStream_t stream) {
    (void)in_sizes; (void)n_in; (void)out_size; (void)ws_size;
    const float* x     = (const float*)d_in[0];
    const float* Wq    = (const float*)d_in[1];
    const float* Wk    = (const float*)d_in[2];
    const float* Wv    = (const float*)d_in[3];
    const float* rel   = (const float*)d_in[4];
    const float* gamma = (const float*)d_in[5];
    const float* beta  = (const float*)d_in[6];
    float* out = (float*)d_out;

    char* ws = (char*)d_ws;
    // Layout (86 MB): [Xb 16MB | Wtb 6MB | QKV 48MB | VT 16MB]
    // relbf (64KB) aliases Xb region: Xb dead after qkv_mfma; conv_rel runs after.
    unsigned short* Xb    = (unsigned short*)ws;
    unsigned short* Wtb   = (unsigned short*)(ws + 16777216);
    unsigned short* QKV   = (unsigned short*)(ws + 23068672);
    unsigned short* VT    = (unsigned short*)(ws + 73400320);
    unsigned short* relbf = (unsigned short*)ws;

    conv_xw<<<7168, 256, 0, stream>>>(x, Wq, Wk, Wv, Xb, Wtb);
    qkv_mfma<<<1536, 256, 0, stream>>>(Xb, Wtb, QKV, VT);
    conv_rel<<<32, 256, 0, stream>>>(rel, relbf);
    attn_mfma<<<1024, 256, 0, stream>>>(QKV, VT, relbf, out);
    layernorm_inplace<<<PB * PS, 256, 0, stream>>>(out, gamma, beta);
}